// Round 9
// baseline (1107.442 us; speedup 1.0000x reference)
//
#include <hip/hip_runtime.h>

typedef __attribute__((ext_vector_type(8))) short short8;
typedef __attribute__((ext_vector_type(4))) float f32x4;
typedef __attribute__((ext_vector_type(4))) int i32x4;

// Problem constants
#define S_LEN 256
#define BATCH 128
#define IN_DIM 1024
#define HID 512
#define G4 2048  // 4*HID

#define SENT 0xFFFFFFFFu  // 2x bf16 NaN; h=o*tanh(c) can never be NaN

// Fused grid: 128 LSTM blocks + 128 GEMM workers = 256 blocks of 512 threads.
// 256 blocks <= 256 CUs -> every block gets a private CU (round-7 measured).
#define LSTM_BLOCKS 128
#define GEMM_WORKERS 128
#define TOT_BLOCKS (LSTM_BLOCKS + GEMM_WORKERS)
// GEMM tiles: 128 rows x 256 cols -> 256 mt (one per timestep) x 8 nt
#define NT_PER_ROW 8
#define N_TILES (256 * NT_PER_ROW)

// progress counters: g_cnt[t] counts finished nt-tiles of timestep t (ready at 8)
__device__ unsigned g_cnt[S_LEN];

__device__ __forceinline__ unsigned short f32_bf16(float f) {
  unsigned int u = __float_as_uint(f);
  u = (u + 0x7FFFu + ((u >> 16) & 1u)) >> 16;  // RNE
  return (unsigned short)u;
}
__device__ __forceinline__ float bf16_f32(unsigned short h) {
  return __uint_as_float(((unsigned int)h) << 16);
}
__device__ __forceinline__ float sigm(float x) { return 1.0f / (1.0f + __expf(-x)); }
__device__ __forceinline__ float tanh_fast(float x) {
  return 1.0f - 2.0f / (__expf(2.0f * x) + 1.0f);
}
__device__ __forceinline__ unsigned ld_cnt(const unsigned* p) {
  return __hip_atomic_load(p, __ATOMIC_RELAXED, __HIP_MEMORY_SCOPE_AGENT);
}
__device__ __forceinline__ unsigned ld_u32_agent(const void* p) {
  return __hip_atomic_load((const unsigned*)p, __ATOMIC_RELAXED, __HIP_MEMORY_SCOPE_AGENT);
}
// Opaque register pin: value becomes an asm output -> compiler cannot
// rematerialize it from its defining load; it must stay register-resident.
__device__ __forceinline__ short8 pin8(short8 x) {
  i32x4 t = __builtin_bit_cast(i32x4, x);
  asm volatile("" : "+v"(t));
  return __builtin_bit_cast(short8, t);
}

__device__ __forceinline__ void cvt4(const float* __restrict__ s,
                                     unsigned short* __restrict__ d, int i) {
  float4 v = *(const float4*)(s + (size_t)i * 4);
  ushort4 o;
  o.x = f32_bf16(v.x); o.y = f32_bf16(v.y); o.z = f32_bf16(v.z); o.w = f32_bf16(v.w);
  *(ushort4*)(d + (size_t)i * 4) = o;
}

// ---------------- prep kernel: weight conversions + bias + ring + counters ----------------
// (x is no longer pre-converted: the GEMM workers read f32 x and convert in-register.)
__global__ void prep(const float* __restrict__ w_ih, const float* __restrict__ w_hh,
                     const float* __restrict__ b_ih, const float* __restrict__ b_hh,
                     unsigned short* __restrict__ wih_bf, unsigned short* __restrict__ whh_bf,
                     float* __restrict__ bias, uint4* __restrict__ hring4) {
  const int gtid = blockIdx.x * blockDim.x + threadIdx.x;
  const int gsz = gridDim.x * blockDim.x;
  if (gtid < G4) bias[gtid] = b_ih[gtid] + b_hh[gtid];
  if (gtid < S_LEN) g_cnt[gtid] = 0u;
  for (int i = gtid; i < 2097152 / 4; i += gsz) cvt4(w_ih, wih_bf, i);
  for (int i = gtid; i < 1048576 / 4; i += gsz) cvt4(w_hh, whh_bf, i);
  const int SLOT4 = BATCH * HID / 8;  // 8192 uint4 per slot
  const int TOT4 = 257 * SLOT4;
  const uint4 z = make_uint4(0u, 0u, 0u, 0u);
  const uint4 sN = make_uint4(SENT, SENT, SENT, SENT);
  for (int k = gtid; k < TOT4; k += gsz) hring4[k] = (k < SLOT4) ? z : sN;
  // kernel end = implicit device-wide release before fused_lstm starts.
}

__device__ __forceinline__ void gl_lds16(const void* g, void* l) {
  __builtin_amdgcn_global_load_lds(
      (const __attribute__((address_space(1))) unsigned int*)g,
      (__attribute__((address_space(3))) unsigned int*)l, 16, 0, 0);
}

// ---------------- fused producer(GEMM) / consumer(recurrence) kernel ----------------
__global__ __launch_bounds__(512, 1) void fused_lstm(
    const unsigned short* __restrict__ whh,  // [2048][512] bf16
    const float* __restrict__ x,             // [256][128][1024] f32 (raw input)
    const unsigned short* __restrict__ wih,  // [2048][1024] bf16
    const float* __restrict__ bias,          // [2048]
    unsigned short* __restrict__ gx,         // [256][128][2048] bf16 (bias folded)
    unsigned* __restrict__ hring,            // [257][128][512] bf16 ring
    float* __restrict__ out) {               // [1] final sum
  __shared__ __align__(16) union {
    struct { unsigned short Hs[2][16][520]; float Gt[16][132]; } L;   // 41,728 B
    struct { unsigned short As[2 * 4096]; unsigned short Bs[2 * 8192]; } G;  // 49,152 B
  } sm;

  const int tid = threadIdx.x;
  const int w = tid >> 6, l = tid & 63;

  if (blockIdx.x >= LSTM_BLOCKS) {
    // ================= GEMM producer role (8 waves, 128x256 tile) =================
    const int wm = w & 1, wn = w >> 1;  // 2x4 wave grid, 64x64 per wave
    const int arow = tid >> 2, akc = tid & 3;  // A staging slot: row, k-chunk
    for (int tile = (int)blockIdx.x - LSTM_BLOCKS; tile < N_TILES; tile += GEMM_WORKERS) {
      const int nt = tile & (NT_PER_ROW - 1), mt = tile >> 3;
      f32x4 acc[4][4];
#pragma unroll
      for (int i = 0; i < 4; i++)
#pragma unroll
        for (int j = 0; j < 4; j++) acc[i][j] = f32x4{0.f, 0.f, 0.f, 0.f};

      const float* xrow = x + (size_t)(mt * 128 + arow) * 1024 + akc * 8;

      // issue: start x f32 loads (to regs) + wih global_load_lds for K-step k0
      auto issueB = [&](int cur, int k0) {
#pragma unroll
        for (int jj = 0; jj < 2; ++jj) {
          int cid = jj * 512 + tid;
          int row = cid >> 2, kc = cid & 3;
          gl_lds16(wih + (size_t)(nt * 256 + row) * 1024 + k0 + kc * 8,
                   sm.G.Bs + cur * 8192 + jj * 4096 + w * 512);
        }
      };
      auto issueX = [&](int k0, float4& xa, float4& xb) {
        xa = *(const float4*)(xrow + k0);
        xb = *(const float4*)(xrow + k0 + 4);
      };
      // commit: convert + ds_write the staged x chunk (16B/thread, conflict-free)
      auto commitX = [&](int cur, const float4& xa, const float4& xb) {
        uint4 o;
        o.x = (unsigned)f32_bf16(xa.x) | ((unsigned)f32_bf16(xa.y) << 16);
        o.y = (unsigned)f32_bf16(xa.z) | ((unsigned)f32_bf16(xa.w) << 16);
        o.z = (unsigned)f32_bf16(xb.x) | ((unsigned)f32_bf16(xb.y) << 16);
        o.w = (unsigned)f32_bf16(xb.z) | ((unsigned)f32_bf16(xb.w) << 16);
        *(uint4*)&sm.G.As[cur * 4096 + tid * 8] = o;
      };

      float4 xa, xb;
      issueX(0, xa, xb);
      issueB(0, 0);
      commitX(0, xa, xb);
      asm volatile("s_waitcnt vmcnt(0) lgkmcnt(0)" ::: "memory");
      __builtin_amdgcn_s_barrier();

      for (int ks = 0; ks < 32; ++ks) {
        const int cur = ks & 1;
        if (ks + 1 < 32) {  // T14 split: issue loads early, commit after MFMAs
          issueX((ks + 1) * 32, xa, xb);
          issueB(cur ^ 1, (ks + 1) * 32);
        }
        short8 a[4], b[4];
#pragma unroll
        for (int i = 0; i < 4; i++)
          a[i] = *(const short8*)&sm.G.As[cur * 4096 +
                                          (wm * 64 + i * 16 + (l & 15)) * 32 + (l >> 4) * 8];
#pragma unroll
        for (int j = 0; j < 4; j++)
          b[j] = *(const short8*)&sm.G.Bs[cur * 8192 +
                                          (wn * 64 + j * 16 + (l & 15)) * 32 + (l >> 4) * 8];
#pragma unroll
        for (int i = 0; i < 4; i++)
#pragma unroll
          for (int j = 0; j < 4; j++)
            acc[i][j] = __builtin_amdgcn_mfma_f32_16x16x32_bf16(a[i], b[j], acc[i][j], 0, 0, 0);
        if (ks + 1 < 32) commitX(cur ^ 1, xa, xb);  // vmcnt-wait lands here, under MFMAs
        __builtin_amdgcn_sched_barrier(0);
        asm volatile("s_waitcnt vmcnt(0) lgkmcnt(0)" ::: "memory");
        __builtin_amdgcn_s_barrier();
      }

      // epilogue: bias + bf16 pack, agent-scope stores (device-visible)
#pragma unroll
      for (int j = 0; j < 4; j++) {
        int cg = nt * 256 + wn * 64 + j * 16 + (l & 15);
        float bv = bias[cg];
#pragma unroll
        for (int i = 0; i < 4; i++) {
          int rbase = mt * 128 + wm * 64 + i * 16 + (l >> 4) * 4;
#pragma unroll
          for (int r = 0; r < 4; r++) {
            unsigned short hv = f32_bf16(acc[i][j][r] + bv);
            __hip_atomic_store(gx + (size_t)(rbase + r) * G4 + cg, hv,
                               __ATOMIC_RELAXED, __HIP_MEMORY_SCOPE_AGENT);
          }
        }
      }
      asm volatile("s_waitcnt vmcnt(0)" ::: "memory");  // this wave's stores complete
      __syncthreads();                                  // all waves drained before publish
      if (tid == 0)
        __hip_atomic_fetch_add(&g_cnt[mt], 1u, __ATOMIC_RELAXED, __HIP_MEMORY_SCOPE_AGENT);
    }
    return;
  }

  // ================= LSTM recurrence role (round-2 protocol) =================
  __builtin_amdgcn_s_setprio(1);  // latency-critical waves stay ahead of GEMM waves
  if (tid >= 256) {               // waves 4..7: barrier-match only (1 per step)
    for (int t = 0; t < S_LEN; t++) __syncthreads();
    return;
  }
  const int m = blockIdx.x & 7;   // batch tile / group
  const int s = blockIdx.x >> 3;  // hidden slice (16 slices of 32 cols)

  // ---- preload W_hh fragments (constant over t), PINNED in registers ----
  short8 bw[16][2];
#pragma unroll
  for (int u = 0; u < 2; u++) {
    int n = (2 * w + u) * 16 + (l & 15);   // local gate-col n = j*4+g
    int jn = n >> 2, g = n & 3;
    int R = g * 512 + s * 32 + jn;         // global gate row
    const unsigned short* base = whh + (size_t)R * 512 + ((l >> 4) * 8);
#pragma unroll
    for (int kk = 0; kk < 16; kk++) bw[kk][u] = pin8(*(const short8*)(base + kk * 32));
  }

  const int b = l & 15;
  const int p = 4 * w + (l >> 4);
  const int gb = m * 16 + b;
  const int colg = s * 32 + 2 * p;
  float c0 = 0.f, c1 = 0.f;
  unsigned hp_last = 0u;  // final-step packed bf16 pair for the fused reduction

  const int SLOTW = BATCH * HID / 2;
  const unsigned long long* hull = (const unsigned long long*)hring;
  const int SLOTQ = BATCH * HID / 4;

  const int skc = tid & 127;
  const int srow = tid >> 7;
  const bool selfst = (((tid >> 3) & 15) == s);
  const size_t qbase = (size_t)(m * 16 + srow) * 128 + skc;

  // ---- initial loads for t=0 (slot 0 valid; gx row 0 gated on producer) ----
  unsigned long long v[8];
#pragma unroll
  for (int it = 0; it < 8; it++)
    v[it] = __hip_atomic_load(&hull[qbase + (size_t)it * 256],
                              __ATOMIC_RELAXED, __HIP_MEMORY_SCOPE_AGENT);
  while (ld_cnt(&g_cnt[0]) != (unsigned)NT_PER_ROW) __builtin_amdgcn_s_sleep(2);
  float2 pg[4];
  {
    size_t base0 = (size_t)gb * G4 + colg;
#pragma unroll
    for (int g = 0; g < 4; g++) {
      unsigned u = ld_u32_agent(gx + base0 + (size_t)g * 512);
      pg[g].x = bf16_f32((unsigned short)(u & 0xFFFFu));
      pg[g].y = bf16_f32((unsigned short)(u >> 16));
    }
  }
  unsigned cn = ld_cnt(&g_cnt[1]);  // readiness of row 1, prefetched off critical path

  for (int t = 0; t < S_LEN; t++) {
    const int buf = t & 1;
    const unsigned long long* src = hull + (size_t)t * SLOTQ;

    // ---- finalize stripe: reload only sentinel lanes (skip self-stripe at t>0) ----
    if (!(selfst && t > 0)) {
      for (;;) {
        int bad = 0;
#pragma unroll
        for (int it = 0; it < 8; it++)
          bad |= (((unsigned)v[it] == SENT) | ((unsigned)(v[it] >> 32) == SENT)) << it;
        if (!bad) break;
#pragma unroll
        for (int it = 0; it < 8; it++)
          if ((bad >> it) & 1)
            v[it] = __hip_atomic_load(&src[qbase + (size_t)it * 256],
                                      __ATOMIC_RELAXED, __HIP_MEMORY_SCOPE_AGENT);
      }
#pragma unroll
      for (int it = 0; it < 8; it++)
        *(unsigned long long*)&sm.L.Hs[buf][it * 2 + srow][skc * 4] = v[it];
    }
    __syncthreads();

    // ---- speculative prefetch for t+1: stripe (non-self) + gated gx ----
    unsigned long long vn[8];
    float2 pgn[4];
    if (t + 1 < S_LEN) {
      if (!selfst) {
        const unsigned long long* srcn = hull + (size_t)(t + 1) * SLOTQ;
#pragma unroll
        for (int it = 0; it < 8; it++)
          vn[it] = __hip_atomic_load(&srcn[qbase + (size_t)it * 256],
                                     __ATOMIC_RELAXED, __HIP_MEMORY_SCOPE_AGENT);
      }
      if (cn != (unsigned)NT_PER_ROW) {  // producer lagging (startup only)
        do {
          __builtin_amdgcn_s_sleep(1);
          cn = ld_cnt(&g_cnt[t + 1]);
        } while (cn != (unsigned)NT_PER_ROW);
      }
      size_t basen = (size_t)((t + 1) * BATCH + gb) * G4 + colg;
#pragma unroll
      for (int g = 0; g < 4; g++) {
        unsigned u = ld_u32_agent(gx + basen + (size_t)g * 512);
        pgn[g].x = bf16_f32((unsigned short)(u & 0xFFFFu));
        pgn[g].y = bf16_f32((unsigned short)(u >> 16));
      }
      cn = (t + 2 < S_LEN) ? ld_cnt(&g_cnt[t + 2]) : (unsigned)NT_PER_ROW;
    }

    // ---- gates tile via MFMA (LDS A-fragments, register B) ----
    f32x4 acc0 = f32x4{0.f, 0.f, 0.f, 0.f};
    f32x4 acc1 = f32x4{0.f, 0.f, 0.f, 0.f};
#pragma unroll
    for (int kk = 0; kk < 16; kk++) {
      short8 a = *(const short8*)&sm.L.Hs[buf][l & 15][kk * 32 + (l >> 4) * 8];
      acc0 = __builtin_amdgcn_mfma_f32_16x16x32_bf16(a, bw[kk][0], acc0, 0, 0, 0);
      acc1 = __builtin_amdgcn_mfma_f32_16x16x32_bf16(a, bw[kk][1], acc1, 0, 0, 0);
    }

    // ---- Gt exchange (own-wave columns only; in-wave lgkmcnt suffices) ----
#pragma unroll
    for (int r = 0; r < 4; r++) {
      sm.L.Gt[(l >> 4) * 4 + r][(2 * w + 0) * 16 + (l & 15)] = acc0[r];
      sm.L.Gt[(l >> 4) * 4 + r][(2 * w + 1) * 16 + (l & 15)] = acc1[r];
    }

    // ---- pointwise: batch b, cols colg / colg+1 ----
    float4 g0 = *(const float4*)&sm.L.Gt[b][8 * p];
    float4 g1 = *(const float4*)&sm.L.Gt[b][8 * p + 4];
    float i0 = sigm(g0.x + pg[0].x), f0 = sigm(g0.y + pg[1].x);
    float gg0 = tanh_fast(g0.z + pg[2].x), o0 = sigm(g0.w + pg[3].x);
    c0 = f0 * c0 + i0 * gg0;
    float h0 = o0 * tanh_fast(c0);
    float i1 = sigm(g1.x + pg[0].y), f1 = sigm(g1.y + pg[1].y);
    float gg1 = tanh_fast(g1.z + pg[2].y), o1 = sigm(g1.w + pg[3].y);
    c1 = f1 * c1 + i1 * gg1;
    float h1 = o1 * tanh_fast(c1);
    unsigned hp = (unsigned)f32_bf16(h0) | ((unsigned)f32_bf16(h1) << 16);
    hp_last = hp;

    // ---- publish h(t+1): ring (peers) + next Hs buffer (self cols) ----
    __hip_atomic_store(&hring[(size_t)(t + 1) * SLOTW + gb * 256 + s * 16 + p], hp,
                       __ATOMIC_RELAXED, __HIP_MEMORY_SCOPE_AGENT);
    *(unsigned*)&sm.L.Hs[buf ^ 1][b][colg] = hp;  // self-stripe bypass

#pragma unroll
    for (int it = 0; it < 8; it++) v[it] = vn[it];
#pragma unroll
    for (int g = 0; g < 4; g++) pg[g] = pgn[g];
  }

  // ---- fused final reduction over h(256), using the bf16-rounded values ----
  {
    float loc = bf16_f32((unsigned short)(hp_last & 0xFFFFu)) +
                bf16_f32((unsigned short)(hp_last >> 16));
#pragma unroll
    for (int off = 32; off > 0; off >>= 1) loc += __shfl_down(loc, off);
    if (l == 0) atomicAdd(out, loc);
  }
}

// ---------------- launch ----------------
extern "C" void kernel_launch(void* const* d_in, const int* in_sizes, int n_in,
                              void* d_out, int out_size, void* d_ws, size_t ws_size,
                              hipStream_t stream) {
  const float* x = (const float*)d_in[0];     // [256][128][1024]
  const float* w_ih = (const float*)d_in[1];  // [2048][1024]
  const float* w_hh = (const float*)d_in[2];  // [2048][512]
  const float* b_ih = (const float*)d_in[3];  // [2048]
  const float* b_hh = (const float*)d_in[4];  // [2048]

  char* ws = (char*)d_ws;
  unsigned short* wih_bf = (unsigned short*)(ws + 67108864);    //  4,194,304 B
  unsigned short* whh_bf = (unsigned short*)(ws + 71303168);    //  2,097,152 B
  float* bias = (float*)(ws + 73400320);                        //      8,192 B
  unsigned* hring = (unsigned*)(ws + 73408512);                 // 33,685,504 B (257 slots)
  unsigned short* gx = (unsigned short*)(ws + 107094016);       // 134,217,728 B bf16

  // prep: weight conversions + bias fuse + ring poison + counters (x handled in-GEMM)
  prep<<<1024, 256, 0, stream>>>(w_ih, w_hh, b_ih, b_hh, wih_bf, whh_bf, bias,
                                 (uint4*)hring);

  // fused producer/consumer, plain launch, 256 blocks -> 1 block/CU
  fused_lstm<<<TOT_BLOCKS, 512, 0, stream>>>(whh_bf, x, wih_bf, bias, gx, hring,
                                             (float*)d_out);
}

// Round 10
// 1057.123 us; speedup vs baseline: 1.0476x; 1.0476x over previous
//
#include <hip/hip_runtime.h>

typedef __attribute__((ext_vector_type(8))) short short8;
typedef __attribute__((ext_vector_type(4))) float f32x4;

// Problem constants
#define S_LEN 256
#define BATCH 128
#define IN_DIM 1024
#define HID 512
#define G4 2048  // 4*HID

#define SENT 0xFFFFFFFFu  // 2x bf16 NaN; h=o*tanh(c) can never be NaN

// Fused grid: 128 LSTM blocks + 128 GEMM workers = 256 blocks of 512 threads.
// 256 blocks <= 256 CUs -> every block gets a private CU (round-7 measured).
#define LSTM_BLOCKS 128
#define GEMM_WORKERS 128
#define TOT_BLOCKS (LSTM_BLOCKS + GEMM_WORKERS)
// GEMM tiles: 128 rows x 256 cols -> 256 mt (one per timestep) x 8 nt
#define NT_PER_ROW 8
#define N_TILES (256 * NT_PER_ROW)

// progress counters: g_cnt[t] counts finished nt-tiles of timestep t (ready at 8)
__device__ unsigned g_cnt[S_LEN];

__device__ __forceinline__ unsigned short f32_bf16(float f) {
  unsigned int u = __float_as_uint(f);
  u = (u + 0x7FFFu + ((u >> 16) & 1u)) >> 16;  // RNE
  return (unsigned short)u;
}
__device__ __forceinline__ float bf16_f32(unsigned short h) {
  return __uint_as_float(((unsigned int)h) << 16);
}
__device__ __forceinline__ float sigm(float x) { return 1.0f / (1.0f + __expf(-x)); }
__device__ __forceinline__ float tanh_fast(float x) {
  return 1.0f - 2.0f / (__expf(2.0f * x) + 1.0f);
}
__device__ __forceinline__ unsigned ld_cnt(const unsigned* p) {
  return __hip_atomic_load(p, __ATOMIC_RELAXED, __HIP_MEMORY_SCOPE_AGENT);
}
__device__ __forceinline__ unsigned ld_u32_agent(const void* p) {
  return __hip_atomic_load((const unsigned*)p, __ATOMIC_RELAXED, __HIP_MEMORY_SCOPE_AGENT);
}

__device__ __forceinline__ void cvt4(const float* __restrict__ s,
                                     unsigned short* __restrict__ d, int i) {
  float4 v = *(const float4*)(s + (size_t)i * 4);
  ushort4 o;
  o.x = f32_bf16(v.x); o.y = f32_bf16(v.y); o.z = f32_bf16(v.z); o.w = f32_bf16(v.w);
  *(ushort4*)(d + (size_t)i * 4) = o;
}

// ---------------- prep kernel: weight conversions + bias + ring + counters ----------------
// (x is NOT pre-converted: GEMM workers read f32 x once per XCD and convert in-register.)
__global__ void prep(const float* __restrict__ w_ih, const float* __restrict__ w_hh,
                     const float* __restrict__ b_ih, const float* __restrict__ b_hh,
                     unsigned short* __restrict__ wih_bf, unsigned short* __restrict__ whh_bf,
                     float* __restrict__ bias, uint4* __restrict__ hring4) {
  const int gtid = blockIdx.x * blockDim.x + threadIdx.x;
  const int gsz = gridDim.x * blockDim.x;
  if (gtid < G4) bias[gtid] = b_ih[gtid] + b_hh[gtid];
  if (gtid < S_LEN) g_cnt[gtid] = 0u;
  for (int i = gtid; i < 2097152 / 4; i += gsz) cvt4(w_ih, wih_bf, i);
  for (int i = gtid; i < 1048576 / 4; i += gsz) cvt4(w_hh, whh_bf, i);
  const int SLOT4 = BATCH * HID / 8;  // 8192 uint4 per slot
  const int TOT4 = 257 * SLOT4;
  const uint4 z = make_uint4(0u, 0u, 0u, 0u);
  const uint4 sN = make_uint4(SENT, SENT, SENT, SENT);
  for (int k = gtid; k < TOT4; k += gsz) hring4[k] = (k < SLOT4) ? z : sN;
  // kernel end = implicit device-wide release before fused_lstm starts.
}

__device__ __forceinline__ void gl_lds16(const void* g, void* l) {
  __builtin_amdgcn_global_load_lds(
      (const __attribute__((address_space(1))) unsigned int*)g,
      (__attribute__((address_space(3))) unsigned int*)l, 16, 0, 0);
}

// ---------------- fused producer(GEMM) / consumer(recurrence) kernel ----------------
__global__ __launch_bounds__(512, 1) void fused_lstm(
    const unsigned short* __restrict__ whh,  // [2048][512] bf16
    const float* __restrict__ x,             // [256][128][1024] f32 (raw input)
    const unsigned short* __restrict__ wih,  // [2048][1024] bf16
    const float* __restrict__ bias,          // [2048]
    unsigned short* __restrict__ gx,         // [256][128][2048] bf16 (bias folded)
    unsigned* __restrict__ hring,            // [257][128][512] bf16 ring
    float* __restrict__ out) {               // [1] final sum
  __shared__ __align__(16) union {
    struct { unsigned short Hs[2][16][520]; float Gt[16][132]; } L;   // 41,728 B
    struct { unsigned short As[2 * 4096]; unsigned short Bs[2 * 8192]; } G;  // 49,152 B
  } sm;

  const int tid = threadIdx.x;
  const int w = tid >> 6, l = tid & 63;

  if (blockIdx.x >= LSTM_BLOCKS) {
    // ================= GEMM producer role (8 waves, 128x256 tile) =================
    // XCD-affine tile map: workers are bid%8-round-robin across XCDs; assign
    // mt-row mt to XCD mt%8 so the 8 workers of one row share one L2 and the
    // f32 x block is fetched from HBM once (heuristic only; correctness-neutral).
    const int wid = (int)blockIdx.x - LSTM_BLOCKS;  // 0..127
    const int xcd = wid & 7;
    const int kk8 = wid >> 3;      // 0..15 within XCD
    const int pp = kk8 >> 3;       // row-pair phase 0/1
    const int nt = kk8 & 7;        // fixed column tile for this worker
    const int wm = w & 1, wn = w >> 1;  // 2x4 wave grid, 64x64 per wave
    const int arow = tid >> 2, akc = tid & 3;  // A staging slot: row, k-chunk

    for (int j = 0; j < 16; ++j) {
      const int mt = xcd + 8 * (2 * j + pp);  // covers all 256 rows across workers
      f32x4 acc[4][4];
#pragma unroll
      for (int i = 0; i < 4; i++)
#pragma unroll
        for (int jj = 0; jj < 4; jj++) acc[i][jj] = f32x4{0.f, 0.f, 0.f, 0.f};

      const float* xrow = x + (size_t)(mt * 128 + arow) * 1024 + akc * 8;

      auto issueB = [&](int cur, int k0) {
#pragma unroll
        for (int jj = 0; jj < 2; ++jj) {
          int cid = jj * 512 + tid;
          int row = cid >> 2, kc = cid & 3;
          gl_lds16(wih + (size_t)(nt * 256 + row) * 1024 + k0 + kc * 8,
                   sm.G.Bs + cur * 8192 + jj * 4096 + w * 512);
        }
      };
      auto issueX = [&](int k0, float4& xa, float4& xb) {
        xa = *(const float4*)(xrow + k0);
        xb = *(const float4*)(xrow + k0 + 4);
      };
      auto commitX = [&](int cur, const float4& xa, const float4& xb) {
        uint4 o;
        o.x = (unsigned)f32_bf16(xa.x) | ((unsigned)f32_bf16(xa.y) << 16);
        o.y = (unsigned)f32_bf16(xa.z) | ((unsigned)f32_bf16(xa.w) << 16);
        o.z = (unsigned)f32_bf16(xb.x) | ((unsigned)f32_bf16(xb.y) << 16);
        o.w = (unsigned)f32_bf16(xb.z) | ((unsigned)f32_bf16(xb.w) << 16);
        *(uint4*)&sm.G.As[cur * 4096 + tid * 8] = o;
      };

      float4 xa, xb;
      issueX(0, xa, xb);
      issueB(0, 0);
      commitX(0, xa, xb);
      asm volatile("s_waitcnt vmcnt(0) lgkmcnt(0)" ::: "memory");
      __builtin_amdgcn_s_barrier();

      for (int ks = 0; ks < 32; ++ks) {
        const int cur = ks & 1;
        if (ks + 1 < 32) {  // T14 split: issue loads early, commit after MFMAs
          issueX((ks + 1) * 32, xa, xb);
          issueB(cur ^ 1, (ks + 1) * 32);
        }
        short8 a[4], b[4];
#pragma unroll
        for (int i = 0; i < 4; i++)
          a[i] = *(const short8*)&sm.G.As[cur * 4096 +
                                          (wm * 64 + i * 16 + (l & 15)) * 32 + (l >> 4) * 8];
#pragma unroll
        for (int jj = 0; jj < 4; jj++)
          b[jj] = *(const short8*)&sm.G.Bs[cur * 8192 +
                                           (wn * 64 + jj * 16 + (l & 15)) * 32 + (l >> 4) * 8];
#pragma unroll
        for (int i = 0; i < 4; i++)
#pragma unroll
          for (int jj = 0; jj < 4; jj++)
            acc[i][jj] =
                __builtin_amdgcn_mfma_f32_16x16x32_bf16(a[i], b[jj], acc[i][jj], 0, 0, 0);
        if (ks + 1 < 32) commitX(cur ^ 1, xa, xb);  // vmcnt-wait lands here, under MFMAs
        __builtin_amdgcn_sched_barrier(0);
        asm volatile("s_waitcnt vmcnt(0) lgkmcnt(0)" ::: "memory");
        __builtin_amdgcn_s_barrier();
      }

      // epilogue: bias + bf16 pack, agent-scope stores (device-visible)
#pragma unroll
      for (int jj = 0; jj < 4; jj++) {
        int cg = nt * 256 + wn * 64 + jj * 16 + (l & 15);
        float bv = bias[cg];
#pragma unroll
        for (int i = 0; i < 4; i++) {
          int rbase = mt * 128 + wm * 64 + i * 16 + (l >> 4) * 4;
#pragma unroll
          for (int r = 0; r < 4; r++) {
            unsigned short hv = f32_bf16(acc[i][jj][r] + bv);
            __hip_atomic_store(gx + (size_t)(rbase + r) * G4 + cg, hv,
                               __ATOMIC_RELAXED, __HIP_MEMORY_SCOPE_AGENT);
          }
        }
      }
      asm volatile("s_waitcnt vmcnt(0)" ::: "memory");  // this wave's stores complete
      __syncthreads();                                  // all waves drained before publish
      if (tid == 0)
        __hip_atomic_fetch_add(&g_cnt[mt], 1u, __ATOMIC_RELAXED, __HIP_MEMORY_SCOPE_AGENT);
    }
    return;
  }

  // ================= LSTM recurrence role (round-2 protocol, verbatim) =================
  __builtin_amdgcn_s_setprio(1);  // latency-critical waves stay ahead of GEMM waves
  if (tid >= 256) {               // waves 4..7: barrier-match only (1 per step)
    for (int t = 0; t < S_LEN; t++) __syncthreads();
    return;
  }
  const int m = blockIdx.x & 7;   // batch tile / group
  const int s = blockIdx.x >> 3;  // hidden slice (16 slices of 32 cols)

  // ---- preload W_hh fragments (constant over t) ----
  short8 bw[16][2];
#pragma unroll
  for (int u = 0; u < 2; u++) {
    int n = (2 * w + u) * 16 + (l & 15);   // local gate-col n = j*4+g
    int jn = n >> 2, g = n & 3;
    int R = g * 512 + s * 32 + jn;         // global gate row
    const unsigned short* base = whh + (size_t)R * 512 + ((l >> 4) * 8);
#pragma unroll
    for (int kk = 0; kk < 16; kk++) bw[kk][u] = *(const short8*)(base + kk * 32);
  }

  const int b = l & 15;
  const int p = 4 * w + (l >> 4);
  const int gb = m * 16 + b;
  const int colg = s * 32 + 2 * p;
  float c0 = 0.f, c1 = 0.f;
  unsigned hp_last = 0u;  // final-step packed bf16 pair for the fused reduction

  const int SLOTW = BATCH * HID / 2;
  const unsigned long long* hull = (const unsigned long long*)hring;
  const int SLOTQ = BATCH * HID / 4;

  const int skc = tid & 127;
  const int srow = tid >> 7;
  const bool selfst = (((tid >> 3) & 15) == s);
  const size_t qbase = (size_t)(m * 16 + srow) * 128 + skc;

  // ---- initial loads for t=0 (slot 0 valid; gx row 0 gated on producer) ----
  unsigned long long v[8];
#pragma unroll
  for (int it = 0; it < 8; it++)
    v[it] = __hip_atomic_load(&hull[qbase + (size_t)it * 256],
                              __ATOMIC_RELAXED, __HIP_MEMORY_SCOPE_AGENT);
  while (ld_cnt(&g_cnt[0]) != (unsigned)NT_PER_ROW) __builtin_amdgcn_s_sleep(2);
  float2 pg[4];
  {
    size_t base0 = (size_t)gb * G4 + colg;
#pragma unroll
    for (int g = 0; g < 4; g++) {
      unsigned u = ld_u32_agent(gx + base0 + (size_t)g * 512);
      pg[g].x = bf16_f32((unsigned short)(u & 0xFFFFu));
      pg[g].y = bf16_f32((unsigned short)(u >> 16));
    }
  }
  unsigned cn = ld_cnt(&g_cnt[1]);  // readiness of row 1, prefetched off critical path

  for (int t = 0; t < S_LEN; t++) {
    const int buf = t & 1;
    const unsigned long long* src = hull + (size_t)t * SLOTQ;

    // ---- finalize stripe: reload only sentinel lanes (skip self-stripe at t>0) ----
    if (!(selfst && t > 0)) {
      for (;;) {
        int bad = 0;
#pragma unroll
        for (int it = 0; it < 8; it++)
          bad |= (((unsigned)v[it] == SENT) | ((unsigned)(v[it] >> 32) == SENT)) << it;
        if (!bad) break;
#pragma unroll
        for (int it = 0; it < 8; it++)
          if ((bad >> it) & 1)
            v[it] = __hip_atomic_load(&src[qbase + (size_t)it * 256],
                                      __ATOMIC_RELAXED, __HIP_MEMORY_SCOPE_AGENT);
      }
#pragma unroll
      for (int it = 0; it < 8; it++)
        *(unsigned long long*)&sm.L.Hs[buf][it * 2 + srow][skc * 4] = v[it];
    }
    __syncthreads();

    // ---- speculative prefetch for t+1: stripe (non-self) + gated gx ----
    unsigned long long vn[8];
    float2 pgn[4];
    if (t + 1 < S_LEN) {
      if (!selfst) {
        const unsigned long long* srcn = hull + (size_t)(t + 1) * SLOTQ;
#pragma unroll
        for (int it = 0; it < 8; it++)
          vn[it] = __hip_atomic_load(&srcn[qbase + (size_t)it * 256],
                                     __ATOMIC_RELAXED, __HIP_MEMORY_SCOPE_AGENT);
      }
      if (cn != (unsigned)NT_PER_ROW) {  // producer lagging (startup only)
        do {
          __builtin_amdgcn_s_sleep(1);
          cn = ld_cnt(&g_cnt[t + 1]);
        } while (cn != (unsigned)NT_PER_ROW);
      }
      size_t basen = (size_t)((t + 1) * BATCH + gb) * G4 + colg;
#pragma unroll
      for (int g = 0; g < 4; g++) {
        unsigned u = ld_u32_agent(gx + basen + (size_t)g * 512);
        pgn[g].x = bf16_f32((unsigned short)(u & 0xFFFFu));
        pgn[g].y = bf16_f32((unsigned short)(u >> 16));
      }
      cn = (t + 2 < S_LEN) ? ld_cnt(&g_cnt[t + 2]) : (unsigned)NT_PER_ROW;
    }

    // ---- gates tile via MFMA (LDS A-fragments, register B) ----
    f32x4 acc0 = f32x4{0.f, 0.f, 0.f, 0.f};
    f32x4 acc1 = f32x4{0.f, 0.f, 0.f, 0.f};
#pragma unroll
    for (int kk = 0; kk < 16; kk++) {
      short8 a = *(const short8*)&sm.L.Hs[buf][l & 15][kk * 32 + (l >> 4) * 8];
      acc0 = __builtin_amdgcn_mfma_f32_16x16x32_bf16(a, bw[kk][0], acc0, 0, 0, 0);
      acc1 = __builtin_amdgcn_mfma_f32_16x16x32_bf16(a, bw[kk][1], acc1, 0, 0, 0);
    }

    // ---- Gt exchange (own-wave columns only; in-wave lgkmcnt suffices) ----
#pragma unroll
    for (int r = 0; r < 4; r++) {
      sm.L.Gt[(l >> 4) * 4 + r][(2 * w + 0) * 16 + (l & 15)] = acc0[r];
      sm.L.Gt[(l >> 4) * 4 + r][(2 * w + 1) * 16 + (l & 15)] = acc1[r];
    }

    // ---- pointwise: batch b, cols colg / colg+1 ----
    float4 g0 = *(const float4*)&sm.L.Gt[b][8 * p];
    float4 g1 = *(const float4*)&sm.L.Gt[b][8 * p + 4];
    float i0 = sigm(g0.x + pg[0].x), f0 = sigm(g0.y + pg[1].x);
    float gg0 = tanh_fast(g0.z + pg[2].x), o0 = sigm(g0.w + pg[3].x);
    c0 = f0 * c0 + i0 * gg0;
    float h0 = o0 * tanh_fast(c0);
    float i1 = sigm(g1.x + pg[0].y), f1 = sigm(g1.y + pg[1].y);
    float gg1 = tanh_fast(g1.z + pg[2].y), o1 = sigm(g1.w + pg[3].y);
    c1 = f1 * c1 + i1 * gg1;
    float h1 = o1 * tanh_fast(c1);
    unsigned hp = (unsigned)f32_bf16(h0) | ((unsigned)f32_bf16(h1) << 16);
    hp_last = hp;

    // ---- publish h(t+1): ring (peers) + next Hs buffer (self cols) ----
    __hip_atomic_store(&hring[(size_t)(t + 1) * SLOTW + gb * 256 + s * 16 + p], hp,
                       __ATOMIC_RELAXED, __HIP_MEMORY_SCOPE_AGENT);
    *(unsigned*)&sm.L.Hs[buf ^ 1][b][colg] = hp;  // self-stripe bypass

#pragma unroll
    for (int it = 0; it < 8; it++) v[it] = vn[it];
#pragma unroll
    for (int g = 0; g < 4; g++) pg[g] = pgn[g];
  }

  // ---- fused final reduction over h(256), using the bf16-rounded values ----
  {
    float loc = bf16_f32((unsigned short)(hp_last & 0xFFFFu)) +
                bf16_f32((unsigned short)(hp_last >> 16));
#pragma unroll
    for (int off = 32; off > 0; off >>= 1) loc += __shfl_down(loc, off);
    if (l == 0) atomicAdd(out, loc);
  }
}

// ---------------- launch ----------------
extern "C" void kernel_launch(void* const* d_in, const int* in_sizes, int n_in,
                              void* d_out, int out_size, void* d_ws, size_t ws_size,
                              hipStream_t stream) {
  const float* x = (const float*)d_in[0];     // [256][128][1024]
  const float* w_ih = (const float*)d_in[1];  // [2048][1024]
  const float* w_hh = (const float*)d_in[2];  // [2048][512]
  const float* b_ih = (const float*)d_in[3];  // [2048]
  const float* b_hh = (const float*)d_in[4];  // [2048]

  char* ws = (char*)d_ws;
  unsigned short* wih_bf = (unsigned short*)(ws + 67108864);    //  4,194,304 B
  unsigned short* whh_bf = (unsigned short*)(ws + 71303168);    //  2,097,152 B
  float* bias = (float*)(ws + 73400320);                        //      8,192 B
  unsigned* hring = (unsigned*)(ws + 73408512);                 // 33,685,504 B (257 slots)
  unsigned short* gx = (unsigned short*)(ws + 107094016);       // 134,217,728 B bf16

  // prep: weight conversions + bias fuse + ring poison + counters (x handled in-GEMM)
  prep<<<1024, 256, 0, stream>>>(w_ih, w_hh, b_ih, b_hh, wih_bf, whh_bf, bias,
                                 (uint4*)hring);

  // fused producer/consumer, plain launch, 256 blocks -> 1 block/CU
  fused_lstm<<<TOT_BLOCKS, 512, 0, stream>>>(whh_bf, x, wih_bf, bias, gx, hring,
                                             (float*)d_out);
}